// Round 2
// baseline (260.339 us; speedup 1.0000x reference)
//
#include <hip/hip_runtime.h>
#include <hip/hip_bf16.h>

#define LRELU_ALPHA 0.2f

constexpr int N   = 8192;
constexpr int FIN = 512;
constexpr int F   = 128;
constexpr int BR  = 32;      // rows per attention block
constexpr int BC  = 64;      // j-tile width (2 MFMA k-steps)
constexpr int KS  = 4;       // j-range splits (grid.y)
constexpr int JW  = N / KS;  // 2048 j per block
constexpr int NTL = JW / BC; // 32 tiles per block

typedef __attribute__((ext_vector_type(4))) float f32x4;
typedef __attribute__((ext_vector_type(8))) short s16x8;
typedef __attribute__((ext_vector_type(4))) short s16x4;
typedef __attribute__((ext_vector_type(4))) int   i32x4;

static __device__ __forceinline__ short f2bf(float x) {
  unsigned u = __float_as_uint(x);
  return (short)((u + 0x7fffu + ((u >> 16) & 1u)) >> 16);   // RNE bf16
}

// ---------------------------------------------------------------------------
// K1: WhbT = (h@w)^T bf16 [F][N]; Wh1 = Wh@a[:128]; Wh2 = Wh@a[128:] (f32).
// 256 blocks x 256 threads, 32x128 tile, K chunks of 64 in LDS.
// ---------------------------------------------------------------------------
__global__ __launch_bounds__(256) void k_wh(
    const float* __restrict__ h, const float* __restrict__ w,
    const float* __restrict__ a, __hip_bfloat16* __restrict__ WhbT,
    float* __restrict__ Wh1, float* __restrict__ Wh2) {
  __shared__ float hl[32][68];
  __shared__ float wl[64][128];
  const int t    = threadIdx.x;
  const int i0   = blockIdx.x * 32;
  const int col4 = (t & 31) * 4;
  const int rq   = t >> 5;
  float acc[4][4] = {};

  for (int k0 = 0; k0 < FIN; k0 += 64) {
#pragma unroll
    for (int j = 0; j < 2; ++j) {
      int c = t + 256 * j;
      int r = c >> 4, kq = c & 15;
      *(f32x4*)&hl[r][kq * 4] =
          *(const f32x4*)(h + (size_t)(i0 + r) * FIN + k0 + kq * 4);
    }
#pragma unroll
    for (int j = 0; j < 8; ++j) {
      int c = t + 256 * j;
      int kr = c >> 5, f4 = (c & 31) * 4;
      *(f32x4*)&wl[kr][f4] = *(const f32x4*)(w + (size_t)(k0 + kr) * F + f4);
    }
    __syncthreads();
#pragma unroll 4
    for (int k4 = 0; k4 < 64; k4 += 4) {
      f32x4 wv[4];
#pragma unroll
      for (int u = 0; u < 4; ++u) wv[u] = *(const f32x4*)&wl[k4 + u][col4];
#pragma unroll
      for (int ri = 0; ri < 4; ++ri) {
        f32x4 hv = *(const f32x4*)&hl[rq * 4 + ri][k4];
#pragma unroll
        for (int u = 0; u < 4; ++u) {
#pragma unroll
          for (int ci = 0; ci < 4; ++ci) acc[ri][ci] += hv[u] * wv[u][ci];
        }
      }
    }
    __syncthreads();
  }
  // WhbT (bf16, transposed)
#pragma unroll
  for (int ci = 0; ci < 4; ++ci) {
    int f = col4 + ci;
    s16x4 o = {f2bf(acc[0][ci]), f2bf(acc[1][ci]),
               f2bf(acc[2][ci]), f2bf(acc[3][ci])};
    *(s16x4*)((short*)WhbT + (size_t)f * N + i0 + rq * 4) = o;
  }
  // Wh1/Wh2 (f32): dot with a, reduce across the 32 threads sharing rows
  f32x4 av1 = *(const f32x4*)(a + col4);
  f32x4 av2 = *(const f32x4*)(a + F + col4);
  float s1[4], s2[4];
#pragma unroll
  for (int ri = 0; ri < 4; ++ri) {
    s1[ri] = acc[ri][0] * av1[0] + acc[ri][1] * av1[1] +
             acc[ri][2] * av1[2] + acc[ri][3] * av1[3];
    s2[ri] = acc[ri][0] * av2[0] + acc[ri][1] * av2[1] +
             acc[ri][2] * av2[2] + acc[ri][3] * av2[3];
  }
#pragma unroll
  for (int off = 1; off < 32; off <<= 1) {
#pragma unroll
    for (int ri = 0; ri < 4; ++ri) {
      s1[ri] += __shfl_xor(s1[ri], off);
      s2[ri] += __shfl_xor(s2[ri], off);
    }
  }
  if ((t & 31) == 0) {
#pragma unroll
    for (int ri = 0; ri < 4; ++ri) {
      Wh1[i0 + rq * 4 + ri] = s1[ri];
      Wh2[i0 + rq * 4 + ri] = s2[ri];
    }
  }
}

// ---------------------------------------------------------------------------
// K2: barrier-free fused GAT attention partials.
// grid (256, KS), block 256 (4 waves). Scores are bounded (|e|<~6) so no max
// subtraction: p = adj ? exp(lrelu(Wh1+Wh2)) : 0. Each lane computes its own
// MFMA A-fragment directly from global adj/Wh2 -> no LDS, no __syncthreads.
// Wave (r,c) split: waves {0,1}: rows 0-15, waves {2,3}: rows 16-31;
// even waves: cols 0-63, odd waves: cols 64-127.
// Writes partial acc [KS][N][F] and partial row-sum l [KS][N] to ws.
// ---------------------------------------------------------------------------
__global__ __launch_bounds__(256, 3) void k_attn(
    const int* __restrict__ adj, const float* __restrict__ Wh1v,
    const float* __restrict__ Wh2v, const __hip_bfloat16* __restrict__ WhbT,
    float* __restrict__ accP, float* __restrict__ lP) {
  const int t    = threadIdx.x;
  const int l    = t & 63;
  const int w    = t >> 6;
  const int wrow = (w >> 1) * 16;
  const int wcol = (w & 1) * 64;
  const int i0   = blockIdx.x * BR;
  const int s    = blockIdx.y;
  const int r16  = l & 15;
  const int ks8  = (l >> 4) * 8;

  const int row  = i0 + wrow + r16;
  const float w1 = Wh1v[row];
  const int* __restrict__ rowp   = adj + (size_t)row * N + (size_t)s * JW;
  const float* __restrict__ w2p  = Wh2v + s * JW;
  const short* bsrc = (const short*)WhbT;
  const short* bp[4];
#pragma unroll
  for (int nb = 0; nb < 4; ++nb)
    bp[nb] = bsrc + (size_t)(wcol + nb * 16 + r16) * N + s * JW;

  f32x4 acc[4] = {};
  float lsum = 0.f;

  // tile-0 operands
  i32x4 a00 = *(const i32x4*)(rowp + ks8);
  i32x4 a01 = *(const i32x4*)(rowp + ks8 + 4);
  i32x4 a10 = *(const i32x4*)(rowp + ks8 + 32);
  i32x4 a11 = *(const i32x4*)(rowp + ks8 + 36);
  f32x4 c00 = *(const f32x4*)(w2p + ks8);
  f32x4 c01 = *(const f32x4*)(w2p + ks8 + 4);
  f32x4 c10 = *(const f32x4*)(w2p + ks8 + 32);
  f32x4 c11 = *(const f32x4*)(w2p + ks8 + 36);

  for (int tl = 0; tl < NTL; ++tl) {
    // prefetch next tile's adj + Wh2 (clamped; duplicate load is harmless)
    const int jn = (tl + 1 < NTL ? tl + 1 : tl) * BC + ks8;
    i32x4 n00 = *(const i32x4*)(rowp + jn);
    i32x4 n01 = *(const i32x4*)(rowp + jn + 4);
    i32x4 n10 = *(const i32x4*)(rowp + jn + 32);
    i32x4 n11 = *(const i32x4*)(rowp + jn + 36);
    f32x4 m00 = *(const f32x4*)(w2p + jn);
    f32x4 m01 = *(const f32x4*)(w2p + jn + 4);
    f32x4 m10 = *(const f32x4*)(w2p + jn + 32);
    f32x4 m11 = *(const f32x4*)(w2p + jn + 36);
    // B fragments for this tile (L2-resident WhbT)
    const int koff = tl * BC + ks8;
    s16x8 bf0[4], bf1[4];
#pragma unroll
    for (int nb = 0; nb < 4; ++nb) {
      bf0[nb] = *(const s16x8*)(bp[nb] + koff);
      bf1[nb] = *(const s16x8*)(bp[nb] + koff + 32);
    }
    // scores -> P (A-fragment layout, in-register)
    float p0[8], p1[8];
#pragma unroll
    for (int u = 0; u < 4; ++u) {
      float x = w1 + c00[u];
      x = fmaxf(x, LRELU_ALPHA * x);
      p0[u] = a00[u] > 0 ? __expf(x) : 0.f;
    }
#pragma unroll
    for (int u = 0; u < 4; ++u) {
      float x = w1 + c01[u];
      x = fmaxf(x, LRELU_ALPHA * x);
      p0[4 + u] = a01[u] > 0 ? __expf(x) : 0.f;
    }
#pragma unroll
    for (int u = 0; u < 4; ++u) {
      float x = w1 + c10[u];
      x = fmaxf(x, LRELU_ALPHA * x);
      p1[u] = a10[u] > 0 ? __expf(x) : 0.f;
    }
#pragma unroll
    for (int u = 0; u < 4; ++u) {
      float x = w1 + c11[u];
      x = fmaxf(x, LRELU_ALPHA * x);
      p1[4 + u] = a11[u] > 0 ? __expf(x) : 0.f;
    }
#pragma unroll
    for (int u = 0; u < 8; ++u) lsum += p0[u] + p1[u];
    s16x8 af0 = {f2bf(p0[0]), f2bf(p0[1]), f2bf(p0[2]), f2bf(p0[3]),
                 f2bf(p0[4]), f2bf(p0[5]), f2bf(p0[6]), f2bf(p0[7])};
    s16x8 af1 = {f2bf(p1[0]), f2bf(p1[1]), f2bf(p1[2]), f2bf(p1[3]),
                 f2bf(p1[4]), f2bf(p1[5]), f2bf(p1[6]), f2bf(p1[7])};
#pragma unroll
    for (int nb = 0; nb < 4; ++nb) {
      acc[nb] = __builtin_amdgcn_mfma_f32_16x16x32_bf16(af0, bf0[nb], acc[nb], 0, 0, 0);
      acc[nb] = __builtin_amdgcn_mfma_f32_16x16x32_bf16(af1, bf1[nb], acc[nb], 0, 0, 0);
    }
    a00 = n00; a01 = n01; a10 = n10; a11 = n11;
    c00 = m00; c01 = m01; c10 = m10; c11 = m11;
  }
  // row-sum: lanes {l, l^16, l^32, l^48} cover the full row's k-slots
  lsum += __shfl_xor(lsum, 16);
  lsum += __shfl_xor(lsum, 32);
  if ((w & 1) == 0 && l < 16)
    lP[(size_t)s * N + i0 + wrow + l] = lsum;
  // partial accumulator (C layout: row=(l>>4)*4+rg, col=l&15)
  float* op = accP + (size_t)s * N * F;
#pragma unroll
  for (int nb = 0; nb < 4; ++nb) {
#pragma unroll
    for (int rg = 0; rg < 4; ++rg) {
      int r = i0 + wrow + (l >> 4) * 4 + rg;
      int c = wcol + nb * 16 + r16;
      op[(size_t)r * F + c] = acc[nb][rg];
    }
  }
}

// ---------------------------------------------------------------------------
// K3: combine partials: out = elu( (sum_s accP) / (sum_s lP) )
// ---------------------------------------------------------------------------
__global__ __launch_bounds__(256) void k_comb(
    const float* __restrict__ accP, const float* __restrict__ lP,
    float* __restrict__ out) {
  const int idx = blockIdx.x * 256 + threadIdx.x;  // one f32x4 per thread
  const int i   = idx >> 5;                        // row (F/4 = 32 per row)
  f32x4 v = {};
  float lt = 0.f;
#pragma unroll
  for (int s = 0; s < KS; ++s) {
    v += *(const f32x4*)(accP + (size_t)s * N * F + (size_t)idx * 4);
    lt += lP[(size_t)s * N + i];
  }
  f32x4 o;
#pragma unroll
  for (int u = 0; u < 4; ++u) {
    float x = v[u] / lt;
    o[u] = x > 0.f ? x : __expf(x) - 1.f;          // ELU
  }
  *(f32x4*)(out + (size_t)idx * 4) = o;
}

// ---------------------------------------------------------------------------
extern "C" void kernel_launch(void* const* d_in, const int* in_sizes, int n_in,
                              void* d_out, int out_size, void* d_ws, size_t ws_size,
                              hipStream_t stream) {
  const float* h   = (const float*)d_in[0];
  const int*   adj = (const int*)d_in[1];
  const float* w   = (const float*)d_in[2];
  const float* a   = (const float*)d_in[3];
  float* out = (float*)d_out;

  // ws: WhbT bf16 [F][N] (2MB) | Wh1 (32KB) | Wh2 (32KB) | lP [KS][N]
  //     (128KB) | accP [KS][N][F] f32 (16MB)   -- total ~18.2 MB
  char* ws = (char*)d_ws;
  __hip_bfloat16* WhbT = (__hip_bfloat16*)ws;
  float* Wh1  = (float*)(ws + (size_t)F * N * 2);
  float* Wh2  = Wh1 + N;
  float* lP   = Wh2 + N;
  float* accP = lP + (size_t)KS * N;

  k_wh<<<N / 32, 256, 0, stream>>>(h, w, a, WhbT, Wh1, Wh2);
  k_attn<<<dim3(N / BR, KS), 256, 0, stream>>>(adj, Wh1, Wh2, WhbT, accP, lP);
  k_comb<<<(N * F / 4) / 256, 256, 0, stream>>>(accP, lP, out);
}

// Round 3
// 219.488 us; speedup vs baseline: 1.1861x; 1.1861x over previous
//
#include <hip/hip_runtime.h>
#include <hip/hip_bf16.h>

#define LRELU_ALPHA 0.2f

constexpr int N   = 8192;
constexpr int FIN = 512;
constexpr int F   = 128;
constexpr int BRW = 16;          // rows per wave
constexpr int BR  = 64;          // rows per block (4 waves, no row sharing)
constexpr int BC  = 32;          // j-tile width (one MFMA k-step)

typedef __attribute__((ext_vector_type(4))) float f32x4;
typedef __attribute__((ext_vector_type(8))) short s16x8;
typedef __attribute__((ext_vector_type(4))) short s16x4;
typedef __attribute__((ext_vector_type(4))) int   i32x4;

static __device__ __forceinline__ short f2bf(float x) {
  unsigned u = __float_as_uint(x);
  return (short)((u + 0x7fffu + ((u >> 16) & 1u)) >> 16);   // RNE bf16
}

// ---------------------------------------------------------------------------
// K1: WhbT = (h@w)^T bf16 [F][N]; Wh1 = Wh@a[:128]; Wh2 = Wh@a[128:] (f32).
// ---------------------------------------------------------------------------
__global__ __launch_bounds__(256) void k_wh(
    const float* __restrict__ h, const float* __restrict__ w,
    const float* __restrict__ a, __hip_bfloat16* __restrict__ WhbT,
    float* __restrict__ Wh1, float* __restrict__ Wh2) {
  __shared__ float hl[32][68];
  __shared__ float wl[64][128];
  const int t    = threadIdx.x;
  const int i0   = blockIdx.x * 32;
  const int col4 = (t & 31) * 4;
  const int rq   = t >> 5;
  float acc[4][4] = {};

  for (int k0 = 0; k0 < FIN; k0 += 64) {
#pragma unroll
    for (int j = 0; j < 2; ++j) {
      int c = t + 256 * j;
      int r = c >> 4, kq = c & 15;
      *(f32x4*)&hl[r][kq * 4] =
          *(const f32x4*)(h + (size_t)(i0 + r) * FIN + k0 + kq * 4);
    }
#pragma unroll
    for (int j = 0; j < 8; ++j) {
      int c = t + 256 * j;
      int kr = c >> 5, f4 = (c & 31) * 4;
      *(f32x4*)&wl[kr][f4] = *(const f32x4*)(w + (size_t)(k0 + kr) * F + f4);
    }
    __syncthreads();
#pragma unroll 4
    for (int k4 = 0; k4 < 64; k4 += 4) {
      f32x4 wv[4];
#pragma unroll
      for (int u = 0; u < 4; ++u) wv[u] = *(const f32x4*)&wl[k4 + u][col4];
#pragma unroll
      for (int ri = 0; ri < 4; ++ri) {
        f32x4 hv = *(const f32x4*)&hl[rq * 4 + ri][k4];
#pragma unroll
        for (int u = 0; u < 4; ++u) {
#pragma unroll
          for (int ci = 0; ci < 4; ++ci) acc[ri][ci] += hv[u] * wv[u][ci];
        }
      }
    }
    __syncthreads();
  }
#pragma unroll
  for (int ci = 0; ci < 4; ++ci) {
    int f = col4 + ci;
    s16x4 o = {f2bf(acc[0][ci]), f2bf(acc[1][ci]),
               f2bf(acc[2][ci]), f2bf(acc[3][ci])};
    *(s16x4*)((short*)WhbT + (size_t)f * N + i0 + rq * 4) = o;
  }
  f32x4 av1 = *(const f32x4*)(a + col4);
  f32x4 av2 = *(const f32x4*)(a + F + col4);
  float s1[4], s2[4];
#pragma unroll
  for (int ri = 0; ri < 4; ++ri) {
    s1[ri] = acc[ri][0] * av1[0] + acc[ri][1] * av1[1] +
             acc[ri][2] * av1[2] + acc[ri][3] * av1[3];
    s2[ri] = acc[ri][0] * av2[0] + acc[ri][1] * av2[1] +
             acc[ri][2] * av2[2] + acc[ri][3] * av2[3];
  }
#pragma unroll
  for (int off = 1; off < 32; off <<= 1) {
#pragma unroll
    for (int ri = 0; ri < 4; ++ri) {
      s1[ri] += __shfl_xor(s1[ri], off);
      s2[ri] += __shfl_xor(s2[ri], off);
    }
  }
  if ((t & 31) == 0) {
#pragma unroll
    for (int ri = 0; ri < 4; ++ri) {
      Wh1[i0 + rq * 4 + ri] = s1[ri];
      Wh2[i0 + rq * 4 + ri] = s2[ri];
    }
  }
}

// ---------------------------------------------------------------------------
// K2: barrier-free fused GAT attention partials.
// grid (128, KS), block 256 = 4 waves; each wave owns 16 rows x 128 cols
// (no duplicated adj loads or score work). BC=32 j-tiles; adj prefetched
// 2 tiles ahead (HBM), B fragments issued at loop top (L2), Wh2 JIT (L1).
// Scores bounded -> p = adj ? exp(lrelu(Wh1+Wh2)) : 0, no online max.
// Writes partial acc [KS][N][F] and partial row-sums l [KS][N].
// ---------------------------------------------------------------------------
template <int KS>
__global__ __launch_bounds__(256) void k_attn(
    const int* __restrict__ adj, const float* __restrict__ Wh1v,
    const float* __restrict__ Wh2v, const __hip_bfloat16* __restrict__ WhbT,
    float* __restrict__ accP, float* __restrict__ lP) {
  constexpr int JW  = N / KS;
  constexpr int NTL = JW / BC;
  const int t   = threadIdx.x;
  const int l   = t & 63;
  const int w   = t >> 6;
  const int r16 = l & 15;
  const int g8  = (l >> 4) * 8;    // k-slot base within tile
  const int i0  = blockIdx.x * BR;
  const int s   = blockIdx.y;

  const int row  = i0 + w * BRW + r16;
  const float w1 = Wh1v[row];
  const int* __restrict__ rowp  = adj + (size_t)row * N + (size_t)s * JW;
  const float* __restrict__ w2p = Wh2v + (size_t)s * JW;
  const short* __restrict__ bq  =
      (const short*)WhbT + (size_t)r16 * N + (size_t)s * JW;

  f32x4 acc[8] = {};
  float lsum = 0.f;

  // prologue: tiles 0 and 1 of adj in registers
  i32x4 aC0 = *(const i32x4*)(rowp + g8);
  i32x4 aC1 = *(const i32x4*)(rowp + g8 + 4);
  i32x4 aP0 = *(const i32x4*)(rowp + BC + g8);
  i32x4 aP1 = *(const i32x4*)(rowp + BC + g8 + 4);

  for (int tl = 0; tl < NTL; ++tl) {
    const int kof = tl * BC + g8;
    // B fragments for this tile (L2-resident WhbT); issue early
    s16x8 bf[8];
#pragma unroll
    for (int nb = 0; nb < 8; ++nb)
      bf[nb] = *(const s16x8*)(bq + (size_t)nb * (16 * N) + kof);
    // adj prefetch, 2 tiles ahead (clamped; duplicate load harmless)
    const int jn = (tl + 2 < NTL ? tl + 2 : tl) * BC + g8;
    i32x4 aN0 = *(const i32x4*)(rowp + jn);
    i32x4 aN1 = *(const i32x4*)(rowp + jn + 4);
    // Wh2 JIT (L1-resident, same addrs across waves)
    f32x4 c0 = *(const f32x4*)(w2p + kof);
    f32x4 c1 = *(const f32x4*)(w2p + kof + 4);
    // scores -> P in A-fragment layout
    float p[8];
#pragma unroll
    for (int u = 0; u < 4; ++u) {
      float x = w1 + c0[u];
      x = fmaxf(x, LRELU_ALPHA * x);
      p[u] = aC0[u] > 0 ? __expf(x) : 0.f;
    }
#pragma unroll
    for (int u = 0; u < 4; ++u) {
      float x = w1 + c1[u];
      x = fmaxf(x, LRELU_ALPHA * x);
      p[4 + u] = aC1[u] > 0 ? __expf(x) : 0.f;
    }
#pragma unroll
    for (int u = 0; u < 8; ++u) lsum += p[u];
    s16x8 af = {f2bf(p[0]), f2bf(p[1]), f2bf(p[2]), f2bf(p[3]),
                f2bf(p[4]), f2bf(p[5]), f2bf(p[6]), f2bf(p[7])};
#pragma unroll
    for (int nb = 0; nb < 8; ++nb)
      acc[nb] = __builtin_amdgcn_mfma_f32_16x16x32_bf16(af, bf[nb], acc[nb],
                                                        0, 0, 0);
    aC0 = aP0; aC1 = aP1; aP0 = aN0; aP1 = aN1;
  }
  // row-sums: lanes {l, l^16, l^32, l^48} hold the row's k-slot partials
  lsum += __shfl_xor(lsum, 16);
  lsum += __shfl_xor(lsum, 32);
  if (l < 16) lP[(size_t)s * N + row] = lsum;
  // partial accumulator (C layout: row=(l>>4)*4+rg, col=l&15)
  float* op = accP + (size_t)s * N * F;
#pragma unroll
  for (int nb = 0; nb < 8; ++nb) {
#pragma unroll
    for (int rg = 0; rg < 4; ++rg) {
      int r = i0 + w * BRW + (l >> 4) * 4 + rg;
      op[(size_t)r * F + nb * 16 + r16] = acc[nb][rg];
    }
  }
}

// ---------------------------------------------------------------------------
// K3: combine partials: out = elu( (sum_s accP) / (sum_s lP) )
// ---------------------------------------------------------------------------
template <int KS>
__global__ __launch_bounds__(256) void k_comb(
    const float* __restrict__ accP, const float* __restrict__ lP,
    float* __restrict__ out) {
  const int idx = blockIdx.x * 256 + threadIdx.x;  // one f32x4 per thread
  const int i   = idx >> 5;                        // row (F/4 = 32 per row)
  f32x4 v = {};
  float lt = 0.f;
#pragma unroll
  for (int s = 0; s < KS; ++s) {
    v += *(const f32x4*)(accP + (size_t)s * N * F + (size_t)idx * 4);
    lt += lP[(size_t)s * N + i];
  }
  f32x4 o;
#pragma unroll
  for (int u = 0; u < 4; ++u) {
    float x = v[u] / lt;
    o[u] = x > 0.f ? x : __expf(x) - 1.f;          // ELU
  }
  *(f32x4*)(out + (size_t)idx * 4) = o;
}

// ---------------------------------------------------------------------------
extern "C" void kernel_launch(void* const* d_in, const int* in_sizes, int n_in,
                              void* d_out, int out_size, void* d_ws, size_t ws_size,
                              hipStream_t stream) {
  const float* h   = (const float*)d_in[0];
  const int*   adj = (const int*)d_in[1];
  const float* w   = (const float*)d_in[2];
  const float* a   = (const float*)d_in[3];
  float* out = (float*)d_out;

  // ws: WhbT bf16 [F][N] | Wh1 [N] | Wh2 [N] | lP [KS][N] | accP [KS][N][F]
  char* ws = (char*)d_ws;
  __hip_bfloat16* WhbT = (__hip_bfloat16*)ws;
  float* Wh1 = (float*)(ws + (size_t)F * N * 2);
  float* Wh2 = Wh1 + N;
  float* lP  = Wh2 + N;

  const size_t fixed = (size_t)F * N * 2 + 2 * (size_t)N * 4;
  const size_t need8 = fixed + 8 * (size_t)N * 4 + 8 * (size_t)N * F * 4;

  k_wh<<<N / 32, 256, 0, stream>>>(h, w, a, WhbT, Wh1, Wh2);
  if (ws_size >= need8) {
    constexpr int KS = 8;
    float* accP = lP + (size_t)KS * N;
    k_attn<KS><<<dim3(N / BR, KS), 256, 0, stream>>>(adj, Wh1, Wh2, WhbT,
                                                     accP, lP);
    k_comb<KS><<<(N * F / 4) / 256, 256, 0, stream>>>(accP, lP, out);
  } else {
    constexpr int KS = 4;
    float* accP = lP + (size_t)KS * N;
    k_attn<KS><<<dim3(N / BR, KS), 256, 0, stream>>>(adj, Wh1, Wh2, WhbT,
                                                     accP, lP);
    k_comb<KS><<<(N * F / 4) / 256, 256, 0, stream>>>(accP, lP, out);
  }
}

// Round 4
// 212.594 us; speedup vs baseline: 1.2246x; 1.0324x over previous
//
#include <hip/hip_runtime.h>
#include <hip/hip_bf16.h>

#define LRELU_ALPHA 0.2f

constexpr int N   = 8192;
constexpr int FIN = 512;
constexpr int F   = 128;
constexpr int BRW = 16;          // rows per wave
constexpr int BR  = 64;          // rows per block (4 waves, no row sharing)
constexpr int BC  = 32;          // j-tile width (one MFMA k-step)

typedef __attribute__((ext_vector_type(4))) float f32x4;
typedef __attribute__((ext_vector_type(8))) short s16x8;
typedef __attribute__((ext_vector_type(4))) short s16x4;
typedef __attribute__((ext_vector_type(4))) int   i32x4;

static __device__ __forceinline__ short f2bf(float x) {
  unsigned u = __float_as_uint(x);
  return (short)((u + 0x7fffu + ((u >> 16) & 1u)) >> 16);   // RNE bf16
}

// ---------------------------------------------------------------------------
// K1: WhbT = (h@w)^T bf16 [F][N]; Wh1 = Wh@a[:128]; Wh2 = Wh@a[128:] (f32).
// ---------------------------------------------------------------------------
__global__ __launch_bounds__(256) void k_wh(
    const float* __restrict__ h, const float* __restrict__ w,
    const float* __restrict__ a, __hip_bfloat16* __restrict__ WhbT,
    float* __restrict__ Wh1, float* __restrict__ Wh2) {
  __shared__ float hl[32][68];
  __shared__ float wl[64][128];
  const int t    = threadIdx.x;
  const int i0   = blockIdx.x * 32;
  const int col4 = (t & 31) * 4;
  const int rq   = t >> 5;
  float acc[4][4] = {};

  for (int k0 = 0; k0 < FIN; k0 += 64) {
#pragma unroll
    for (int j = 0; j < 2; ++j) {
      int c = t + 256 * j;
      int r = c >> 4, kq = c & 15;
      *(f32x4*)&hl[r][kq * 4] =
          *(const f32x4*)(h + (size_t)(i0 + r) * FIN + k0 + kq * 4);
    }
#pragma unroll
    for (int j = 0; j < 8; ++j) {
      int c = t + 256 * j;
      int kr = c >> 5, f4 = (c & 31) * 4;
      *(f32x4*)&wl[kr][f4] = *(const f32x4*)(w + (size_t)(k0 + kr) * F + f4);
    }
    __syncthreads();
#pragma unroll 4
    for (int k4 = 0; k4 < 64; k4 += 4) {
      f32x4 wv[4];
#pragma unroll
      for (int u = 0; u < 4; ++u) wv[u] = *(const f32x4*)&wl[k4 + u][col4];
#pragma unroll
      for (int ri = 0; ri < 4; ++ri) {
        f32x4 hv = *(const f32x4*)&hl[rq * 4 + ri][k4];
#pragma unroll
        for (int u = 0; u < 4; ++u) {
#pragma unroll
          for (int ci = 0; ci < 4; ++ci) acc[ri][ci] += hv[u] * wv[u][ci];
        }
      }
    }
    __syncthreads();
  }
#pragma unroll
  for (int ci = 0; ci < 4; ++ci) {
    int f = col4 + ci;
    s16x4 o = {f2bf(acc[0][ci]), f2bf(acc[1][ci]),
               f2bf(acc[2][ci]), f2bf(acc[3][ci])};
    *(s16x4*)((short*)WhbT + (size_t)f * N + i0 + rq * 4) = o;
  }
  f32x4 av1 = *(const f32x4*)(a + col4);
  f32x4 av2 = *(const f32x4*)(a + F + col4);
  float s1[4], s2[4];
#pragma unroll
  for (int ri = 0; ri < 4; ++ri) {
    s1[ri] = acc[ri][0] * av1[0] + acc[ri][1] * av1[1] +
             acc[ri][2] * av1[2] + acc[ri][3] * av1[3];
    s2[ri] = acc[ri][0] * av2[0] + acc[ri][1] * av2[1] +
             acc[ri][2] * av2[2] + acc[ri][3] * av2[3];
  }
#pragma unroll
  for (int off = 1; off < 32; off <<= 1) {
#pragma unroll
    for (int ri = 0; ri < 4; ++ri) {
      s1[ri] += __shfl_xor(s1[ri], off);
      s2[ri] += __shfl_xor(s2[ri], off);
    }
  }
  if ((t & 31) == 0) {
#pragma unroll
    for (int ri = 0; ri < 4; ++ri) {
      Wh1[i0 + rq * 4 + ri] = s1[ri];
      Wh2[i0 + rq * 4 + ri] = s2[ri];
    }
  }
}

// ---------------------------------------------------------------------------
// K2: barrier-free fused GAT attention partials, register-pipelined.
// grid (128, KS), block 256 = 4 waves; each wave owns 16 rows x 128 cols.
// Explicit 2-deep pipeline: B fragments double-buffered (bfA/bfB), adj
// prefetched 2 tiles ahead. amdgpu_waves_per_eu(1,4): min=1 removes the
// occupancy-driven VGPR cap (round 3: 64 VGPRs serialized the L2 loads).
// ---------------------------------------------------------------------------
template <int KS>
__global__ __launch_bounds__(256) __attribute__((amdgpu_waves_per_eu(1, 4)))
void k_attn(
    const int* __restrict__ adj, const float* __restrict__ Wh1v,
    const float* __restrict__ Wh2v, const __hip_bfloat16* __restrict__ WhbT,
    float* __restrict__ accP, float* __restrict__ lP) {
  constexpr int JW  = N / KS;
  constexpr int NTL = JW / BC;     // even
  const int t   = threadIdx.x;
  const int l   = t & 63;
  const int w   = t >> 6;
  const int r16 = l & 15;
  const int g8  = (l >> 4) * 8;    // k-slot base within tile
  const int i0  = blockIdx.x * BR;
  const int s   = blockIdx.y;

  const int row  = i0 + w * BRW + r16;
  const float w1 = Wh1v[row];
  const int* __restrict__ rowp  = adj + (size_t)row * N + (size_t)s * JW;
  const float* __restrict__ w2p = Wh2v + (size_t)s * JW;
  const short* __restrict__ bq  =
      (const short*)WhbT + (size_t)r16 * N + (size_t)s * JW;
  const size_t bstep = (size_t)16 * N;

  f32x4 acc[8] = {};
  float lsum = 0.f;
  s16x8 bfA[8], bfB[8];

  // prologue: B for tile 0; adj for tiles 0 and 1
#pragma unroll
  for (int nb = 0; nb < 8; ++nb)
    bfA[nb] = *(const s16x8*)(bq + nb * bstep + g8);
  i32x4 a0 = *(const i32x4*)(rowp + g8);
  i32x4 a1 = *(const i32x4*)(rowp + g8 + 4);
  i32x4 b0 = *(const i32x4*)(rowp + BC + g8);
  i32x4 b1 = *(const i32x4*)(rowp + BC + g8 + 4);

  for (int tl = 0; tl < NTL; tl += 2) {
    // ================= even tile tl (bfA) =================
    {
      const int kn = (tl + 1) * BC + g8;   // B for tile tl+1
#pragma unroll
      for (int nb = 0; nb < 8; ++nb)
        bfB[nb] = *(const s16x8*)(bq + nb * bstep + kn);
    }
    {
      const int kof = tl * BC + g8;
      f32x4 c0 = *(const f32x4*)(w2p + kof);        // L1-resident
      f32x4 c1 = *(const f32x4*)(w2p + kof + 4);
      float p[8];
#pragma unroll
      for (int u = 0; u < 4; ++u) {
        float x = w1 + c0[u];
        x = fmaxf(x, LRELU_ALPHA * x);
        p[u] = a0[u] > 0 ? __expf(x) : 0.f;
      }
#pragma unroll
      for (int u = 0; u < 4; ++u) {
        float x = w1 + c1[u];
        x = fmaxf(x, LRELU_ALPHA * x);
        p[4 + u] = a1[u] > 0 ? __expf(x) : 0.f;
      }
#pragma unroll
      for (int u = 0; u < 8; ++u) lsum += p[u];
      s16x8 af = {f2bf(p[0]), f2bf(p[1]), f2bf(p[2]), f2bf(p[3]),
                  f2bf(p[4]), f2bf(p[5]), f2bf(p[6]), f2bf(p[7])};
      // adj prefetch: tile tl+2 (clamped; dup load harmless/unused)
      const int j2 = (tl + 2 < NTL ? tl + 2 : tl) * BC + g8;
      a0 = *(const i32x4*)(rowp + j2);
      a1 = *(const i32x4*)(rowp + j2 + 4);
#pragma unroll
      for (int nb = 0; nb < 8; ++nb)
        acc[nb] = __builtin_amdgcn_mfma_f32_16x16x32_bf16(af, bfA[nb],
                                                          acc[nb], 0, 0, 0);
    }
    // ================= odd tile tl+1 (bfB) =================
    {
      const int kn = (tl + 2 < NTL ? tl + 2 : tl) * BC + g8;  // B for tl+2
#pragma unroll
      for (int nb = 0; nb < 8; ++nb)
        bfA[nb] = *(const s16x8*)(bq + nb * bstep + kn);
    }
    {
      const int kof = (tl + 1) * BC + g8;
      f32x4 c0 = *(const f32x4*)(w2p + kof);
      f32x4 c1 = *(const f32x4*)(w2p + kof + 4);
      float p[8];
#pragma unroll
      for (int u = 0; u < 4; ++u) {
        float x = w1 + c0[u];
        x = fmaxf(x, LRELU_ALPHA * x);
        p[u] = b0[u] > 0 ? __expf(x) : 0.f;
      }
#pragma unroll
      for (int u = 0; u < 4; ++u) {
        float x = w1 + c1[u];
        x = fmaxf(x, LRELU_ALPHA * x);
        p[4 + u] = b1[u] > 0 ? __expf(x) : 0.f;
      }
#pragma unroll
      for (int u = 0; u < 8; ++u) lsum += p[u];
      s16x8 af = {f2bf(p[0]), f2bf(p[1]), f2bf(p[2]), f2bf(p[3]),
                  f2bf(p[4]), f2bf(p[5]), f2bf(p[6]), f2bf(p[7])};
      // adj prefetch: tile tl+3
      const int j3 = (tl + 3 < NTL ? tl + 3 : tl + 1) * BC + g8;
      b0 = *(const i32x4*)(rowp + j3);
      b1 = *(const i32x4*)(rowp + j3 + 4);
#pragma unroll
      for (int nb = 0; nb < 8; ++nb)
        acc[nb] = __builtin_amdgcn_mfma_f32_16x16x32_bf16(af, bfB[nb],
                                                          acc[nb], 0, 0, 0);
    }
  }
  // row-sums: lanes {l, l^16, l^32, l^48} hold the row's k-slot partials
  lsum += __shfl_xor(lsum, 16);
  lsum += __shfl_xor(lsum, 32);
  if (l < 16) lP[(size_t)s * N + row] = lsum;
  // partial accumulator (C layout: row=(l>>4)*4+rg, col=l&15)
  float* op = accP + (size_t)s * N * F;
#pragma unroll
  for (int nb = 0; nb < 8; ++nb) {
#pragma unroll
    for (int rg = 0; rg < 4; ++rg) {
      int r = i0 + w * BRW + (l >> 4) * 4 + rg;
      op[(size_t)r * F + nb * 16 + r16] = acc[nb][rg];
    }
  }
}

// ---------------------------------------------------------------------------
// K3: combine partials: out = elu( (sum_s accP) / (sum_s lP) )
// ---------------------------------------------------------------------------
template <int KS>
__global__ __launch_bounds__(256) void k_comb(
    const float* __restrict__ accP, const float* __restrict__ lP,
    float* __restrict__ out) {
  const int idx = blockIdx.x * 256 + threadIdx.x;  // one f32x4 per thread
  const int i   = idx >> 5;                        // row (F/4 = 32 per row)
  f32x4 v = {};
  float lt = 0.f;
#pragma unroll
  for (int s = 0; s < KS; ++s) {
    v += *(const f32x4*)(accP + (size_t)s * N * F + (size_t)idx * 4);
    lt += lP[(size_t)s * N + i];
  }
  f32x4 o;
#pragma unroll
  for (int u = 0; u < 4; ++u) {
    float x = v[u] / lt;
    o[u] = x > 0.f ? x : __expf(x) - 1.f;          // ELU
  }
  *(f32x4*)(out + (size_t)idx * 4) = o;
}

// ---------------------------------------------------------------------------
extern "C" void kernel_launch(void* const* d_in, const int* in_sizes, int n_in,
                              void* d_out, int out_size, void* d_ws, size_t ws_size,
                              hipStream_t stream) {
  const float* h   = (const float*)d_in[0];
  const int*   adj = (const int*)d_in[1];
  const float* w   = (const float*)d_in[2];
  const float* a   = (const float*)d_in[3];
  float* out = (float*)d_out;

  // ws: WhbT bf16 [F][N] | Wh1 [N] | Wh2 [N] | lP [KS][N] | accP [KS][N][F]
  char* ws = (char*)d_ws;
  __hip_bfloat16* WhbT = (__hip_bfloat16*)ws;
  float* Wh1 = (float*)(ws + (size_t)F * N * 2);
  float* Wh2 = Wh1 + N;
  float* lP  = Wh2 + N;

  const size_t fixed = (size_t)F * N * 2 + 2 * (size_t)N * 4;
  const size_t need8 = fixed + 8 * (size_t)N * 4 + 8 * (size_t)N * F * 4;

  k_wh<<<N / 32, 256, 0, stream>>>(h, w, a, WhbT, Wh1, Wh2);
  if (ws_size >= need8) {
    constexpr int KS = 8;
    float* accP = lP + (size_t)KS * N;
    k_attn<KS><<<dim3(N / BR, KS), 256, 0, stream>>>(adj, Wh1, Wh2, WhbT,
                                                     accP, lP);
    k_comb<KS><<<(N * F / 4) / 256, 256, 0, stream>>>(accP, lP, out);
  } else {
    constexpr int KS = 4;
    float* accP = lP + (size_t)KS * N;
    k_attn<KS><<<dim3(N / BR, KS), 256, 0, stream>>>(adj, Wh1, Wh2, WhbT,
                                                     accP, lP);
    k_comb<KS><<<(N * F / 4) / 256, 256, 0, stream>>>(accP, lP, out);
  }
}

// Round 5
// 130.685 us; speedup vs baseline: 1.9921x; 1.6268x over previous
//
#include <hip/hip_runtime.h>
#include <hip/hip_bf16.h>

#define LRELU_ALPHA 0.2f

constexpr int N   = 8192;
constexpr int FIN = 512;
constexpr int F   = 128;
constexpr int BRW = 16;          // rows per wave
constexpr int BR  = 64;          // rows per block (4 waves)
constexpr int BK  = 64;          // j per LDS tile (2 MFMA k-steps)

typedef __attribute__((ext_vector_type(4))) float f32x4;
typedef __attribute__((ext_vector_type(8))) short s16x8;
typedef __attribute__((ext_vector_type(4))) short s16x4;
typedef __attribute__((ext_vector_type(4))) int   i32x4;

static __device__ __forceinline__ short f2bf(float x) {
  unsigned u = __float_as_uint(x);
  return (short)((u + 0x7fffu + ((u >> 16) & 1u)) >> 16);   // RNE bf16
}

// ---------------------------------------------------------------------------
// K1: WhbT = (h@w)^T bf16 [F][N]; Wh1 = Wh@a[:128]; Wh2 = Wh@a[128:] (f32).
// ---------------------------------------------------------------------------
__global__ __launch_bounds__(256) void k_wh(
    const float* __restrict__ h, const float* __restrict__ w,
    const float* __restrict__ a, __hip_bfloat16* __restrict__ WhbT,
    float* __restrict__ Wh1, float* __restrict__ Wh2) {
  __shared__ float hl[32][68];
  __shared__ float wl[64][128];
  const int t    = threadIdx.x;
  const int i0   = blockIdx.x * 32;
  const int col4 = (t & 31) * 4;
  const int rq   = t >> 5;
  float acc[4][4] = {};

  for (int k0 = 0; k0 < FIN; k0 += 64) {
#pragma unroll
    for (int j = 0; j < 2; ++j) {
      int c = t + 256 * j;
      int r = c >> 4, kq = c & 15;
      *(f32x4*)&hl[r][kq * 4] =
          *(const f32x4*)(h + (size_t)(i0 + r) * FIN + k0 + kq * 4);
    }
#pragma unroll
    for (int j = 0; j < 8; ++j) {
      int c = t + 256 * j;
      int kr = c >> 5, f4 = (c & 31) * 4;
      *(f32x4*)&wl[kr][f4] = *(const f32x4*)(w + (size_t)(k0 + kr) * F + f4);
    }
    __syncthreads();
#pragma unroll 4
    for (int k4 = 0; k4 < 64; k4 += 4) {
      f32x4 wv[4];
#pragma unroll
      for (int u = 0; u < 4; ++u) wv[u] = *(const f32x4*)&wl[k4 + u][col4];
#pragma unroll
      for (int ri = 0; ri < 4; ++ri) {
        f32x4 hv = *(const f32x4*)&hl[rq * 4 + ri][k4];
#pragma unroll
        for (int u = 0; u < 4; ++u) {
#pragma unroll
          for (int ci = 0; ci < 4; ++ci) acc[ri][ci] += hv[u] * wv[u][ci];
        }
      }
    }
    __syncthreads();
  }
#pragma unroll
  for (int ci = 0; ci < 4; ++ci) {
    int f = col4 + ci;
    s16x4 o = {f2bf(acc[0][ci]), f2bf(acc[1][ci]),
               f2bf(acc[2][ci]), f2bf(acc[3][ci])};
    *(s16x4*)((short*)WhbT + (size_t)f * N + i0 + rq * 4) = o;
  }
  f32x4 av1 = *(const f32x4*)(a + col4);
  f32x4 av2 = *(const f32x4*)(a + F + col4);
  float s1[4], s2[4];
#pragma unroll
  for (int ri = 0; ri < 4; ++ri) {
    s1[ri] = acc[ri][0] * av1[0] + acc[ri][1] * av1[1] +
             acc[ri][2] * av1[2] + acc[ri][3] * av1[3];
    s2[ri] = acc[ri][0] * av2[0] + acc[ri][1] * av2[1] +
             acc[ri][2] * av2[2] + acc[ri][3] * av2[3];
  }
#pragma unroll
  for (int off = 1; off < 32; off <<= 1) {
#pragma unroll
    for (int ri = 0; ri < 4; ++ri) {
      s1[ri] += __shfl_xor(s1[ri], off);
      s2[ri] += __shfl_xor(s2[ri], off);
    }
  }
  if ((t & 31) == 0) {
#pragma unroll
    for (int ri = 0; ri < 4; ++ri) {
      Wh1[i0 + rq * 4 + ri] = s1[ri];
      Wh2[i0 + rq * 4 + ri] = s2[ri];
    }
  }
}

// ---------------------------------------------------------------------------
// K2: fused GAT attention partials, LDS-pipelined (m97-style).
// grid (128, KS), block 256 = 4 waves; block = 64 rows x 128 cols x JW j.
// Per BK=64 j-tile: B-tile [128 f][64 k] bf16 staged once per block into
// double-buffered XOR-swizzled LDS (reg-staged: linear coalesced global
// reads, swizzled ds_write; swizzled ds_read -> conflict-free b128).
// adj/Wh2 roll through registers 2 tiles ahead, issued AFTER stage loads
// (FIFO vmcnt: waiting on stage never drains them). One barrier per tile.
// ---------------------------------------------------------------------------
template <int KS>
__global__ __launch_bounds__(256) __attribute__((amdgpu_waves_per_eu(1, 4)))
void k_attn(
    const int* __restrict__ adj, const float* __restrict__ Wh1v,
    const float* __restrict__ Wh2v, const __hip_bfloat16* __restrict__ WhbT,
    float* __restrict__ accP, float* __restrict__ lP) {
  constexpr int JW  = N / KS;
  constexpr int NTL = JW / BK;     // 16 for KS=8 (even)
  __shared__ __align__(16) short Bl[2][F * BK];   // 2 x 16 KB

  const int t   = threadIdx.x;
  const int l   = t & 63;
  const int w   = t >> 6;
  const int r16 = l & 15;
  const int g8  = (l >> 4) * 8;
  const int i0  = blockIdx.x * BR;
  const int s   = blockIdx.y;

  const int row  = i0 + w * BRW + r16;
  const float w1 = Wh1v[row];
  const int* __restrict__ rowp   = adj + (size_t)row * N + (size_t)s * JW;
  const float* __restrict__ w2p  = Wh2v + (size_t)s * JW;
  const short* __restrict__ bsrc = (const short*)WhbT + (size_t)s * JW;

  // staging map: chunk c = t + 256*q (16 B each); row fr = c>>3, gran = c&7
  int ldsoff[4]; size_t goff[4];
#pragma unroll
  for (int q = 0; q < 4; ++q) {
    int c  = t + 256 * q;
    int fr = c >> 3;
    ldsoff[q] = (c * 16) ^ ((fr & 7) << 4);           // swizzled LDS byte
    goff[q]   = (size_t)fr * N + (c & 7) * 8;         // linear global (shorts)
  }
  const int sw = (r16 & 7) << 4;                       // read-side XOR

  f32x4 acc[8] = {};
  float lsum = 0.f;
  s16x8 sv[4];

  // score operands for one tile, in registers
  i32x4 aA0, aA1, aA2, aA3, aB0, aB1, aB2, aB3;
  f32x4 cA0, cA1, cA2, cA3, cB0, cB1, cB2, cB3;

#define LOAD_SCORE(A0, A1, A2, A3, C0, C1, C2, C3, off)                      \
  A0 = *(const i32x4*)(rowp + (off) + g8);                                   \
  A1 = *(const i32x4*)(rowp + (off) + g8 + 4);                               \
  A2 = *(const i32x4*)(rowp + (off) + g8 + 32);                              \
  A3 = *(const i32x4*)(rowp + (off) + g8 + 36);                              \
  C0 = *(const f32x4*)(w2p + (off) + g8);                                    \
  C1 = *(const f32x4*)(w2p + (off) + g8 + 4);                                \
  C2 = *(const f32x4*)(w2p + (off) + g8 + 32);                               \
  C3 = *(const f32x4*)(w2p + (off) + g8 + 36);

  auto scores = [&](const i32x4& x0, const i32x4& x1, const i32x4& x2,
                    const i32x4& x3, const f32x4& y0, const f32x4& y1,
                    const f32x4& y2, const f32x4& y3, s16x8& af0, s16x8& af1) {
    float p[16];
#pragma unroll
    for (int u = 0; u < 4; ++u) {
      float x = w1 + y0[u]; x = fmaxf(x, LRELU_ALPHA * x);
      p[u] = x0[u] > 0 ? __expf(x) : 0.f;
    }
#pragma unroll
    for (int u = 0; u < 4; ++u) {
      float x = w1 + y1[u]; x = fmaxf(x, LRELU_ALPHA * x);
      p[4 + u] = x1[u] > 0 ? __expf(x) : 0.f;
    }
#pragma unroll
    for (int u = 0; u < 4; ++u) {
      float x = w1 + y2[u]; x = fmaxf(x, LRELU_ALPHA * x);
      p[8 + u] = x2[u] > 0 ? __expf(x) : 0.f;
    }
#pragma unroll
    for (int u = 0; u < 4; ++u) {
      float x = w1 + y3[u]; x = fmaxf(x, LRELU_ALPHA * x);
      p[12 + u] = x3[u] > 0 ? __expf(x) : 0.f;
    }
#pragma unroll
    for (int u = 0; u < 16; ++u) lsum += p[u];
    af0 = s16x8{f2bf(p[0]),  f2bf(p[1]),  f2bf(p[2]),  f2bf(p[3]),
                f2bf(p[4]),  f2bf(p[5]),  f2bf(p[6]),  f2bf(p[7])};
    af1 = s16x8{f2bf(p[8]),  f2bf(p[9]),  f2bf(p[10]), f2bf(p[11]),
                f2bf(p[12]), f2bf(p[13]), f2bf(p[14]), f2bf(p[15])};
  };

  auto mfma_tile = [&](const char* pb, s16x8 af0, s16x8 af1) {
#pragma unroll
    for (int nb = 0; nb < 8; ++nb) {
      const int rbase = (nb * 16 + r16) * 128;
      s16x8 b0 = *(const s16x8*)(pb + rbase + ((g8 * 2) ^ sw));
      s16x8 b1 = *(const s16x8*)(pb + rbase + ((g8 * 2 + 64) ^ sw));
      acc[nb] = __builtin_amdgcn_mfma_f32_16x16x32_bf16(af0, b0, acc[nb], 0, 0, 0);
      acc[nb] = __builtin_amdgcn_mfma_f32_16x16x32_bf16(af1, b1, acc[nb], 0, 0, 0);
    }
  };

  // ---- prologue: stage tile 0 -> buf0; score-regs for tiles 0,1 ----
#pragma unroll
  for (int q = 0; q < 4; ++q) sv[q] = *(const s16x8*)(bsrc + goff[q]);
  LOAD_SCORE(aA0, aA1, aA2, aA3, cA0, cA1, cA2, cA3, 0)
  LOAD_SCORE(aB0, aB1, aB2, aB3, cB0, cB1, cB2, cB3, BK)
#pragma unroll
  for (int q = 0; q < 4; ++q)
    *(s16x8*)((char*)&Bl[0][0] + ldsoff[q]) = sv[q];
  __syncthreads();

  for (int tl = 0; tl < NTL; tl += 2) {
    // ======== even tile tl: read buf0, stage tl+1 -> buf1, refill A ========
    {
      const size_t tn = (size_t)(tl + 1 < NTL ? tl + 1 : NTL - 1) * BK;
#pragma unroll
      for (int q = 0; q < 4; ++q)
        sv[q] = *(const s16x8*)(bsrc + goff[q] + tn);
    }
    {
      s16x8 af0, af1;
      scores(aA0, aA1, aA2, aA3, cA0, cA1, cA2, cA3, af0, af1);
      const int tp = (tl + 2 < NTL ? tl + 2 : tl) * BK;   // clamp: dup unused
      LOAD_SCORE(aA0, aA1, aA2, aA3, cA0, cA1, cA2, cA3, tp)
#pragma unroll
      for (int q = 0; q < 4; ++q)
        *(s16x8*)((char*)&Bl[1][0] + ldsoff[q]) = sv[q];
      mfma_tile((const char*)&Bl[0][0], af0, af1);
    }
    __syncthreads();
    // ======== odd tile tl+1: read buf1, stage tl+2 -> buf0, refill B ========
    {
      const size_t tn = (size_t)(tl + 2 < NTL ? tl + 2 : NTL - 1) * BK;
#pragma unroll
      for (int q = 0; q < 4; ++q)
        sv[q] = *(const s16x8*)(bsrc + goff[q] + tn);
    }
    {
      s16x8 af0, af1;
      scores(aB0, aB1, aB2, aB3, cB0, cB1, cB2, cB3, af0, af1);
      const int tp = (tl + 3 < NTL ? tl + 3 : tl + 1) * BK;
      LOAD_SCORE(aB0, aB1, aB2, aB3, cB0, cB1, cB2, cB3, tp)
#pragma unroll
      for (int q = 0; q < 4; ++q)
        *(s16x8*)((char*)&Bl[0][0] + ldsoff[q]) = sv[q];
      mfma_tile((const char*)&Bl[1][0], af0, af1);
    }
    __syncthreads();
  }
#undef LOAD_SCORE

  // row-sums: lanes {l, l^16, l^32, l^48} hold the row's k-slot partials
  lsum += __shfl_xor(lsum, 16);
  lsum += __shfl_xor(lsum, 32);
  if (l < 16) lP[(size_t)s * N + row] = lsum;
  // partial accumulator (C layout: row=(l>>4)*4+rg, col=l&15)
  float* op = accP + (size_t)s * N * F;
#pragma unroll
  for (int nb = 0; nb < 8; ++nb) {
#pragma unroll
    for (int rg = 0; rg < 4; ++rg) {
      int r = i0 + w * BRW + (l >> 4) * 4 + rg;
      op[(size_t)r * F + nb * 16 + r16] = acc[nb][rg];
    }
  }
}

// ---------------------------------------------------------------------------
// K3: combine partials: out = elu( (sum_s accP) / (sum_s lP) )
// ---------------------------------------------------------------------------
template <int KS>
__global__ __launch_bounds__(256) void k_comb(
    const float* __restrict__ accP, const float* __restrict__ lP,
    float* __restrict__ out) {
  const int idx = blockIdx.x * 256 + threadIdx.x;  // one f32x4 per thread
  const int i   = idx >> 5;                        // row (F/4 = 32 per row)
  f32x4 v = {};
  float lt = 0.f;
#pragma unroll
  for (int s = 0; s < KS; ++s) {
    v += *(const f32x4*)(accP + (size_t)s * N * F + (size_t)idx * 4);
    lt += lP[(size_t)s * N + i];
  }
  f32x4 o;
#pragma unroll
  for (int u = 0; u < 4; ++u) {
    float x = v[u] / lt;
    o[u] = x > 0.f ? x : __expf(x) - 1.f;          // ELU
  }
  *(f32x4*)(out + (size_t)idx * 4) = o;
}

// ---------------------------------------------------------------------------
extern "C" void kernel_launch(void* const* d_in, const int* in_sizes, int n_in,
                              void* d_out, int out_size, void* d_ws, size_t ws_size,
                              hipStream_t stream) {
  const float* h   = (const float*)d_in[0];
  const int*   adj = (const int*)d_in[1];
  const float* w   = (const float*)d_in[2];
  const float* a   = (const float*)d_in[3];
  float* out = (float*)d_out;

  // ws: WhbT bf16 [F][N] | Wh1 [N] | Wh2 [N] | lP [KS][N] | accP [KS][N][F]
  char* ws = (char*)d_ws;
  __hip_bfloat16* WhbT = (__hip_bfloat16*)ws;
  float* Wh1 = (float*)(ws + (size_t)F * N * 2);
  float* Wh2 = Wh1 + N;
  float* lP  = Wh2 + N;

  const size_t fixed = (size_t)F * N * 2 + 2 * (size_t)N * 4;
  const size_t need8 = fixed + 8 * (size_t)N * 4 + 8 * (size_t)N * F * 4;

  k_wh<<<N / 32, 256, 0, stream>>>(h, w, a, WhbT, Wh1, Wh2);
  if (ws_size >= need8) {
    constexpr int KS = 8;
    float* accP = lP + (size_t)KS * N;
    k_attn<KS><<<dim3(N / BR, KS), 256, 0, stream>>>(adj, Wh1, Wh2, WhbT,
                                                     accP, lP);
    k_comb<KS><<<(N * F / 4) / 256, 256, 0, stream>>>(accP, lP, out);
  } else {
    constexpr int KS = 4;
    float* accP = lP + (size_t)KS * N;
    k_attn<KS><<<dim3(N / BR, KS), 256, 0, stream>>>(adj, Wh1, Wh2, WhbT,
                                                     accP, lP);
    k_comb<KS><<<(N * F / 4) / 256, 256, 0, stream>>>(accP, lP, out);
  }
}